// Round 5
// baseline (652.163 us; speedup 1.0000x reference)
//
#include <hip/hip_runtime.h>

#define NN 50000
#define NE 800000
#define TE (NE + NN)

__device__ __forceinline__ float lrelu02(float x) { return x >= 0.f ? x : 0.2f * x; }

__global__ void k_count(const int* __restrict__ ei, int* __restrict__ counts) {
    int e = blockIdx.x * blockDim.x + threadIdx.x;
    if (e >= TE) return;
    int dst = (e < NE) ? ei[NE + e] : (e - NE);
    atomicAdd(&counts[dst], 1);
}

__global__ void k_bsum(const int* __restrict__ counts, int* __restrict__ bsums) {
    __shared__ int sm[1024];
    int i = blockIdx.x * 1024 + threadIdx.x;
    sm[threadIdx.x] = (i < NN) ? counts[i] : 0;
    __syncthreads();
    for (int off = 512; off > 0; off >>= 1) {
        if ((int)threadIdx.x < off) sm[threadIdx.x] += sm[threadIdx.x + off];
        __syncthreads();
    }
    if (threadIdx.x == 0) bsums[blockIdx.x] = sm[0];
}

__global__ void k_bscan(const int* __restrict__ bsums, int* __restrict__ bex, int nb) {
    int l = threadIdx.x;
    int v = (l < nb) ? bsums[l] : 0;
    int orig = v;
    for (int d = 1; d < 64; d <<= 1) {
        int t = __shfl_up(v, d);
        if (l >= d) v += t;
    }
    if (l <= nb) bex[l] = v - orig;
}

__global__ void k_scan(const int* __restrict__ counts, const int* __restrict__ bex,
                       int* __restrict__ rowptr, int* __restrict__ cursor) {
    __shared__ int sm[1024];
    int t = threadIdx.x;
    int i = blockIdx.x * 1024 + t;
    int c = (i < NN) ? counts[i] : 0;
    sm[t] = c;
    __syncthreads();
    for (int off = 1; off < 1024; off <<= 1) {
        int v = (t >= off) ? sm[t - off] : 0;
        __syncthreads();
        sm[t] += v;
        __syncthreads();
    }
    int ex = bex[blockIdx.x] + sm[t] - c;
    if (i <= NN) rowptr[i] = ex;
    if (i < NN) cursor[i] = ex;
}

__global__ void k_scatter(const int* __restrict__ ei, int* __restrict__ cursor, int* __restrict__ csr) {
    int e = blockIdx.x * blockDim.x + threadIdx.x;
    if (e >= TE) return;
    int src, dst;
    if (e < NE) { src = ei[e]; dst = ei[NE + e]; }
    else { src = e - NE; dst = src; }
    int pos = atomicAdd(&cursor[dst], 1);
    csr[pos] = src;
}

// GEMM X[N,128] @ W[128,128] -> XS[N,128], plus AL[n] = {als0, als1, ald0, ald1}
// Round-3 structure (proven fastest): no LDS; W from global (L2-hot 64 KiB),
// X rows via wave-uniform scalar loads. 4 waves x 8 rows = 32 rows/block.
__global__ __launch_bounds__(256) void k_gemm(const float* __restrict__ X, const float* __restrict__ W,
                                              const float* __restrict__ as_, const float* __restrict__ ad_,
                                              float* __restrict__ XS, float* __restrict__ AL) {
    int wv = __builtin_amdgcn_readfirstlane(threadIdx.x >> 6);
    int lane = threadIdx.x & 63;
    float a0 = as_[lane], a1 = as_[64 + lane];
    float d0 = ad_[lane], d1 = ad_[64 + lane];
    int row0 = blockIdx.x * 32 + wv * 8;
    if (row0 >= NN) return;   // NN % 8 == 0, full 8-row groups only
    float acc[8][2];
#pragma unroll
    for (int r = 0; r < 8; r++) { acc[r][0] = 0.f; acc[r][1] = 0.f; }
#pragma unroll 4
    for (int kk = 0; kk < 128; kk += 4) {
        float w0[4], w1[4];
#pragma unroll
        for (int i = 0; i < 4; i++) {
            w0[i] = W[(kk + i) * 128 + lane];
            w1[i] = W[(kk + i) * 128 + 64 + lane];
        }
#pragma unroll
        for (int r = 0; r < 8; r++) {
            float4 xv = *(const float4*)(X + (size_t)(row0 + r) * 128 + kk);
            acc[r][0] = fmaf(xv.x, w0[0], fmaf(xv.y, w0[1], fmaf(xv.z, w0[2], fmaf(xv.w, w0[3], acc[r][0]))));
            acc[r][1] = fmaf(xv.x, w1[0], fmaf(xv.y, w1[1], fmaf(xv.z, w1[2], fmaf(xv.w, w1[3], acc[r][1]))));
        }
    }
#pragma unroll
    for (int r = 0; r < 8; r++) {
        int row = row0 + r;
        XS[(size_t)row * 128 + lane] = acc[r][0];
        XS[(size_t)row * 128 + 64 + lane] = acc[r][1];
        float s0 = acc[r][0] * a0, s1 = acc[r][1] * a1;
        float t0 = acc[r][0] * d0, t1 = acc[r][1] * d1;
#pragma unroll
        for (int off = 32; off > 0; off >>= 1) {
            s0 += __shfl_xor(s0, off);
            s1 += __shfl_xor(s1, off);
            t0 += __shfl_xor(t0, off);
            t1 += __shfl_xor(t1, off);
        }
        if (lane == 0) {
            float4 v; v.x = s0; v.y = s1; v.z = t0; v.w = t1;
            *(float4*)(AL + (size_t)row * 4) = v;
        }
    }
}

// Aggregation: one wave per dst node; whole-wave coalesced row gather
// (float2/lane = 512 B/instr), 16 independent edge loads in flight.
// Uniform-index __shfl broadcasts (readlane). No segment-max (logits bounded,
// exp safe in fp32; normalized alpha identical).
template <int LAST>
__global__ __launch_bounds__(256) void k_agg(const float* __restrict__ XS, const float* __restrict__ AL,
                                             const int* __restrict__ rowptr, const int* __restrict__ csr,
                                             const float* __restrict__ bias, const float* __restrict__ lp_w,
                                             const float* __restrict__ lp_b, const float* __restrict__ prelu_a,
                                             float* __restrict__ out) {
    int wv = threadIdx.x >> 6, lane = threadIdx.x & 63;
    int n = blockIdx.x * 4 + wv;
    if (n >= NN) return;
    int beg = rowptr[n], end = rowptr[n + 1];
    float2 aldv = *(const float2*)(AL + (size_t)n * 4 + 2);
    float ald0 = aldv.x, ald1 = aldv.y;
    float acc_lo = 0.f, acc_hi = 0.f, den0 = 0.f, den1 = 0.f;
    for (int base = beg; base < end; base += 64) {
        int i = base + lane;
        float w0 = 0.f, w1 = 0.f;
        int sv = 0;
        if (i < end) {
            sv = csr[i];
            float2 av = *(const float2*)(AL + (size_t)sv * 4);
            w0 = __expf(lrelu02(av.x + ald0));
            w1 = __expf(lrelu02(av.y + ald1));
        }
        den0 += w0;
        den1 += w1;
        int cnt = min(64, end - base);
        int j = 0;
        for (; j + 16 <= cnt; j += 16) {
            int s[16];
            float ww[16];
#pragma unroll
            for (int jj = 0; jj < 16; jj++) {
                s[jj] = __shfl(sv, j + jj);                      // uniform idx -> readlane
                float q0 = __shfl(w0, j + jj), q1 = __shfl(w1, j + jj);
                ww[jj] = (lane < 32) ? q0 : q1;
            }
            float2 xv[16];
#pragma unroll
            for (int jj = 0; jj < 16; jj++)
                xv[jj] = *(const float2*)(XS + (size_t)s[jj] * 128 + 2 * lane);
#pragma unroll
            for (int jj = 0; jj < 16; jj++) {
                acc_lo = fmaf(ww[jj], xv[jj].x, acc_lo);
                acc_hi = fmaf(ww[jj], xv[jj].y, acc_hi);
            }
        }
        if (j < cnt) {
            int rem = cnt - j;   // 1..15
            int s[15];
            float ww[15];
            for (int jj = 0; jj < rem; jj++) {
                s[jj] = __shfl(sv, j + jj);
                float q0 = __shfl(w0, j + jj), q1 = __shfl(w1, j + jj);
                ww[jj] = (lane < 32) ? q0 : q1;
            }
            float2 xv[15];
            for (int jj = 0; jj < rem; jj++)
                xv[jj] = *(const float2*)(XS + (size_t)s[jj] * 128 + 2 * lane);
            for (int jj = 0; jj < rem; jj++) {
                acc_lo = fmaf(ww[jj], xv[jj].x, acc_lo);
                acc_hi = fmaf(ww[jj], xv[jj].y, acc_hi);
            }
        }
    }
#pragma unroll
    for (int off = 32; off > 0; off >>= 1) {
        den0 += __shfl_xor(den0, off);
        den1 += __shfl_xor(den1, off);
    }
    float pa = prelu_a[0];
    float densel = (lane < 32) ? den0 : den1;
    float inv = 1.f / (densel + 1e-16f);
    if (LAST) {
        float hlo = acc_lo * inv, hhi = acc_hi * inv;
        float olo = __shfl_xor(hlo, 32), ohi = __shfl_xor(hhi, 32);
        float p = 0.f;
        if (lane < 32) {
            int c = 2 * lane;
            float v0 = 0.5f * (hlo + olo) + bias[c];
            float v1 = 0.5f * (hhi + ohi) + bias[c + 1];
            v0 = v0 >= 0.f ? v0 : pa * v0;
            v1 = v1 >= 0.f ? v1 : pa * v1;
            p = v0 * lp_w[c] + v1 * lp_w[c + 1];
        }
#pragma unroll
        for (int off = 32; off > 0; off >>= 1) p += __shfl_xor(p, off);
        if (lane == 0) out[n] = p + lp_b[0];
    } else {
        int c = 2 * lane;
        float2 bv = *(const float2*)(bias + c);
        float v0 = acc_lo * inv + bv.x;
        float v1 = acc_hi * inv + bv.y;
        v0 = v0 >= 0.f ? v0 : pa * v0;
        v1 = v1 >= 0.f ? v1 : pa * v1;
        float2 o; o.x = v0; o.y = v1;
        *(float2*)(out + (size_t)n * 128 + c) = o;
    }
}

extern "C" void kernel_launch(void* const* d_in, const int* in_sizes, int n_in,
                              void* d_out, int out_size, void* d_ws, size_t ws_size,
                              hipStream_t stream) {
    const float* x   = (const float*)d_in[0];
    const int*   ei  = (const int*)d_in[1];
    const float* W1  = (const float*)d_in[2];
    const float* as1 = (const float*)d_in[3];
    const float* ad1 = (const float*)d_in[4];
    const float* b1  = (const float*)d_in[5];
    const float* W2  = (const float*)d_in[6];
    const float* as2 = (const float*)d_in[7];
    const float* ad2 = (const float*)d_in[8];
    const float* b2  = (const float*)d_in[9];
    const float* W3  = (const float*)d_in[10];
    const float* as3 = (const float*)d_in[11];
    const float* ad3 = (const float*)d_in[12];
    const float* b3  = (const float*)d_in[13];
    const float* lpw = (const float*)d_in[14];
    const float* lpb = (const float*)d_in[15];
    const float* pa  = (const float*)d_in[16];
    float* out = (float*)d_out;

    char* ws = (char*)d_ws;
    size_t off = 0;
    auto alloc = [&](size_t bytes) {
        void* p = ws + off;
        off = (off + bytes + 255) & ~(size_t)255;
        return p;
    };
    int*   rowptr = (int*)alloc((NN + 1) * sizeof(int));
    int*   cursor = (int*)alloc((NN + 1) * sizeof(int));
    int*   counts = (int*)alloc((size_t)NN * sizeof(int));
    int*   bsums  = (int*)alloc(64 * sizeof(int));
    int*   bex    = (int*)alloc(64 * sizeof(int));
    int*   csr    = (int*)alloc((size_t)TE * sizeof(int));
    float* al     = (float*)alloc((size_t)NN * 4 * sizeof(float));
    float* xs     = (float*)alloc((size_t)NN * 128 * sizeof(float));
    float* h      = (float*)alloc((size_t)NN * 128 * sizeof(float));
    (void)ws_size; (void)n_in; (void)in_sizes; (void)out_size;

    const int NB = (NN + 1023) / 1024;       // 49
    const int GEMM_GRID = (NN + 31) / 32;    // 1563

    hipMemsetAsync(counts, 0, (size_t)NN * sizeof(int), stream);
    k_count<<<(TE + 255) / 256, 256, 0, stream>>>(ei, counts);
    k_bsum<<<NB, 1024, 0, stream>>>(counts, bsums);
    k_bscan<<<1, 64, 0, stream>>>(bsums, bex, NB);
    k_scan<<<NB, 1024, 0, stream>>>(counts, bex, rowptr, cursor);
    k_scatter<<<(TE + 255) / 256, 256, 0, stream>>>(ei, cursor, csr);

    k_gemm<<<GEMM_GRID, 256, 0, stream>>>(x, W1, as1, ad1, xs, al);
    k_agg<0><<<(NN + 3) / 4, 256, 0, stream>>>(xs, al, rowptr, csr, b1, nullptr, nullptr, pa, h);
    k_gemm<<<GEMM_GRID, 256, 0, stream>>>(h, W2, as2, ad2, xs, al);
    k_agg<0><<<(NN + 3) / 4, 256, 0, stream>>>(xs, al, rowptr, csr, b2, nullptr, nullptr, pa, h);
    k_gemm<<<GEMM_GRID, 256, 0, stream>>>(h, W3, as3, ad3, xs, al);
    k_agg<1><<<(NN + 3) / 4, 256, 0, stream>>>(xs, al, rowptr, csr, b3, lpw, lpb, pa, out);
}

// Round 6
// 507.882 us; speedup vs baseline: 1.2841x; 1.2841x over previous
//
#include <hip/hip_runtime.h>

#define NN 50000
#define NE 800000
#define TE (NE + NN)

__device__ __forceinline__ float lrelu02(float x) { return x >= 0.f ? x : 0.2f * x; }

__global__ void k_count(const int* __restrict__ ei, int* __restrict__ counts) {
    int e = blockIdx.x * blockDim.x + threadIdx.x;
    if (e >= TE) return;
    int dst = (e < NE) ? ei[NE + e] : (e - NE);
    atomicAdd(&counts[dst], 1);
}

__global__ void k_bsum(const int* __restrict__ counts, int* __restrict__ bsums) {
    __shared__ int sm[1024];
    int i = blockIdx.x * 1024 + threadIdx.x;
    sm[threadIdx.x] = (i < NN) ? counts[i] : 0;
    __syncthreads();
    for (int off = 512; off > 0; off >>= 1) {
        if ((int)threadIdx.x < off) sm[threadIdx.x] += sm[threadIdx.x + off];
        __syncthreads();
    }
    if (threadIdx.x == 0) bsums[blockIdx.x] = sm[0];
}

__global__ void k_bscan(const int* __restrict__ bsums, int* __restrict__ bex, int nb) {
    int l = threadIdx.x;
    int v = (l < nb) ? bsums[l] : 0;
    int orig = v;
    for (int d = 1; d < 64; d <<= 1) {
        int t = __shfl_up(v, d);
        if (l >= d) v += t;
    }
    if (l <= nb) bex[l] = v - orig;
}

__global__ void k_scan(const int* __restrict__ counts, const int* __restrict__ bex,
                       int* __restrict__ rowptr, int* __restrict__ cursor) {
    __shared__ int sm[1024];
    int t = threadIdx.x;
    int i = blockIdx.x * 1024 + t;
    int c = (i < NN) ? counts[i] : 0;
    sm[t] = c;
    __syncthreads();
    for (int off = 1; off < 1024; off <<= 1) {
        int v = (t >= off) ? sm[t - off] : 0;
        __syncthreads();
        sm[t] += v;
        __syncthreads();
    }
    int ex = bex[blockIdx.x] + sm[t] - c;
    if (i <= NN) rowptr[i] = ex;
    if (i < NN) cursor[i] = ex;
}

__global__ void k_scatter(const int* __restrict__ ei, int* __restrict__ cursor, int* __restrict__ csr) {
    int e = blockIdx.x * blockDim.x + threadIdx.x;
    if (e >= TE) return;
    int src, dst;
    if (e < NE) { src = ei[e]; dst = ei[NE + e]; }
    else { src = e - NE; dst = src; }
    int pos = atomicAdd(&cursor[dst], 1);
    csr[pos] = src;
}

// GEMM X[N,128] @ W[128,128] -> XS[N,128], plus AL[n] = {als0, als1, ald0, ald1}
// No LDS; W from global (L2-hot 64 KiB), X rows wave-uniform. 16 rows/wave
// (doubles FMA per W-load vs round 3, halves W L2 traffic). unroll 1 on the
// k-loop to cap register pressure.
__global__ __launch_bounds__(256) void k_gemm(const float* __restrict__ X, const float* __restrict__ W,
                                              const float* __restrict__ as_, const float* __restrict__ ad_,
                                              float* __restrict__ XS, float* __restrict__ AL) {
    int wv = __builtin_amdgcn_readfirstlane(threadIdx.x >> 6);
    int lane = threadIdx.x & 63;
    float a0 = as_[lane], a1 = as_[64 + lane];
    float d0 = ad_[lane], d1 = ad_[64 + lane];
    int row0 = blockIdx.x * 64 + wv * 16;
    if (row0 >= NN) return;   // NN % 16 == 0, full 16-row groups only
    float acc[16][2];
#pragma unroll
    for (int r = 0; r < 16; r++) { acc[r][0] = 0.f; acc[r][1] = 0.f; }
#pragma unroll 1
    for (int kk = 0; kk < 128; kk += 4) {
        float w0[4], w1[4];
#pragma unroll
        for (int i = 0; i < 4; i++) {
            w0[i] = W[(kk + i) * 128 + lane];
            w1[i] = W[(kk + i) * 128 + 64 + lane];
        }
#pragma unroll
        for (int r = 0; r < 16; r++) {
            float4 xv = *(const float4*)(X + (size_t)(row0 + r) * 128 + kk);
            acc[r][0] = fmaf(xv.x, w0[0], fmaf(xv.y, w0[1], fmaf(xv.z, w0[2], fmaf(xv.w, w0[3], acc[r][0]))));
            acc[r][1] = fmaf(xv.x, w1[0], fmaf(xv.y, w1[1], fmaf(xv.z, w1[2], fmaf(xv.w, w1[3], acc[r][1]))));
        }
    }
#pragma unroll
    for (int r = 0; r < 16; r++) {
        int row = row0 + r;
        XS[(size_t)row * 128 + lane] = acc[r][0];
        XS[(size_t)row * 128 + 64 + lane] = acc[r][1];
        float s0 = acc[r][0] * a0, s1 = acc[r][1] * a1;
        float t0 = acc[r][0] * d0, t1 = acc[r][1] * d1;
#pragma unroll
        for (int off = 32; off > 0; off >>= 1) {
            s0 += __shfl_xor(s0, off);
            s1 += __shfl_xor(s1, off);
            t0 += __shfl_xor(t0, off);
            t1 += __shfl_xor(t1, off);
        }
        if (lane == 0) {
            float4 v; v.x = s0; v.y = s1; v.z = t0; v.w = t1;
            *(float4*)(AL + (size_t)row * 4) = v;
        }
    }
}

// Aggregation: one wave per dst node; whole-wave coalesced row gather
// (float2/lane = 512 B/instr). 16-deep, then 8-deep, then scalar tail —
// ALL array accesses compile-time indexed inside #pragma unroll loops
// (runtime-indexed arrays spill to scratch: round-5 lesson).
template <int LAST>
__global__ __launch_bounds__(256) void k_agg(const float* __restrict__ XS, const float* __restrict__ AL,
                                             const int* __restrict__ rowptr, const int* __restrict__ csr,
                                             const float* __restrict__ bias, const float* __restrict__ lp_w,
                                             const float* __restrict__ lp_b, const float* __restrict__ prelu_a,
                                             float* __restrict__ out) {
    int wv = threadIdx.x >> 6, lane = threadIdx.x & 63;
    int n = blockIdx.x * 4 + wv;
    if (n >= NN) return;
    int beg = rowptr[n], end = rowptr[n + 1];
    float2 aldv = *(const float2*)(AL + (size_t)n * 4 + 2);
    float ald0 = aldv.x, ald1 = aldv.y;
    float acc_lo = 0.f, acc_hi = 0.f, den0 = 0.f, den1 = 0.f;
    for (int base = beg; base < end; base += 64) {
        int i = base + lane;
        float w0 = 0.f, w1 = 0.f;
        int sv = 0;
        if (i < end) {
            sv = csr[i];
            float2 av = *(const float2*)(AL + (size_t)sv * 4);
            w0 = __expf(lrelu02(av.x + ald0));
            w1 = __expf(lrelu02(av.y + ald1));
        }
        den0 += w0;
        den1 += w1;
        int cnt = min(64, end - base);
        int j = 0;
        for (; j + 16 <= cnt; j += 16) {
            int s[16];
            float ww[16];
#pragma unroll
            for (int jj = 0; jj < 16; jj++) {
                s[jj] = __shfl(sv, j + jj);                      // uniform idx -> readlane
                float q0 = __shfl(w0, j + jj), q1 = __shfl(w1, j + jj);
                ww[jj] = (lane < 32) ? q0 : q1;
            }
            float2 xv[16];
#pragma unroll
            for (int jj = 0; jj < 16; jj++)
                xv[jj] = *(const float2*)(XS + (size_t)s[jj] * 128 + 2 * lane);
#pragma unroll
            for (int jj = 0; jj < 16; jj++) {
                acc_lo = fmaf(ww[jj], xv[jj].x, acc_lo);
                acc_hi = fmaf(ww[jj], xv[jj].y, acc_hi);
            }
        }
        for (; j + 8 <= cnt; j += 8) {
            int s[8];
            float ww[8];
#pragma unroll
            for (int jj = 0; jj < 8; jj++) {
                s[jj] = __shfl(sv, j + jj);
                float q0 = __shfl(w0, j + jj), q1 = __shfl(w1, j + jj);
                ww[jj] = (lane < 32) ? q0 : q1;
            }
            float2 xv[8];
#pragma unroll
            for (int jj = 0; jj < 8; jj++)
                xv[jj] = *(const float2*)(XS + (size_t)s[jj] * 128 + 2 * lane);
#pragma unroll
            for (int jj = 0; jj < 8; jj++) {
                acc_lo = fmaf(ww[jj], xv[jj].x, acc_lo);
                acc_hi = fmaf(ww[jj], xv[jj].y, acc_hi);
            }
        }
        for (; j < cnt; j++) {
            int s = __shfl(sv, j);
            float q0 = __shfl(w0, j), q1 = __shfl(w1, j);
            float w = (lane < 32) ? q0 : q1;
            float2 xv = *(const float2*)(XS + (size_t)s * 128 + 2 * lane);
            acc_lo = fmaf(w, xv.x, acc_lo);
            acc_hi = fmaf(w, xv.y, acc_hi);
        }
    }
#pragma unroll
    for (int off = 32; off > 0; off >>= 1) {
        den0 += __shfl_xor(den0, off);
        den1 += __shfl_xor(den1, off);
    }
    float pa = prelu_a[0];
    float densel = (lane < 32) ? den0 : den1;
    float inv = 1.f / (densel + 1e-16f);
    if (LAST) {
        float hlo = acc_lo * inv, hhi = acc_hi * inv;
        float olo = __shfl_xor(hlo, 32), ohi = __shfl_xor(hhi, 32);
        float p = 0.f;
        if (lane < 32) {
            int c = 2 * lane;
            float v0 = 0.5f * (hlo + olo) + bias[c];
            float v1 = 0.5f * (hhi + ohi) + bias[c + 1];
            v0 = v0 >= 0.f ? v0 : pa * v0;
            v1 = v1 >= 0.f ? v1 : pa * v1;
            p = v0 * lp_w[c] + v1 * lp_w[c + 1];
        }
#pragma unroll
        for (int off = 32; off > 0; off >>= 1) p += __shfl_xor(p, off);
        if (lane == 0) out[n] = p + lp_b[0];
    } else {
        int c = 2 * lane;
        float2 bv = *(const float2*)(bias + c);
        float v0 = acc_lo * inv + bv.x;
        float v1 = acc_hi * inv + bv.y;
        v0 = v0 >= 0.f ? v0 : pa * v0;
        v1 = v1 >= 0.f ? v1 : pa * v1;
        float2 o; o.x = v0; o.y = v1;
        *(float2*)(out + (size_t)n * 128 + c) = o;
    }
}

extern "C" void kernel_launch(void* const* d_in, const int* in_sizes, int n_in,
                              void* d_out, int out_size, void* d_ws, size_t ws_size,
                              hipStream_t stream) {
    const float* x   = (const float*)d_in[0];
    const int*   ei  = (const int*)d_in[1];
    const float* W1  = (const float*)d_in[2];
    const float* as1 = (const float*)d_in[3];
    const float* ad1 = (const float*)d_in[4];
    const float* b1  = (const float*)d_in[5];
    const float* W2  = (const float*)d_in[6];
    const float* as2 = (const float*)d_in[7];
    const float* ad2 = (const float*)d_in[8];
    const float* b2  = (const float*)d_in[9];
    const float* W3  = (const float*)d_in[10];
    const float* as3 = (const float*)d_in[11];
    const float* ad3 = (const float*)d_in[12];
    const float* b3  = (const float*)d_in[13];
    const float* lpw = (const float*)d_in[14];
    const float* lpb = (const float*)d_in[15];
    const float* pa  = (const float*)d_in[16];
    float* out = (float*)d_out;

    char* ws = (char*)d_ws;
    size_t off = 0;
    auto alloc = [&](size_t bytes) {
        void* p = ws + off;
        off = (off + bytes + 255) & ~(size_t)255;
        return p;
    };
    int*   rowptr = (int*)alloc((NN + 1) * sizeof(int));
    int*   cursor = (int*)alloc((NN + 1) * sizeof(int));
    int*   counts = (int*)alloc((size_t)NN * sizeof(int));
    int*   bsums  = (int*)alloc(64 * sizeof(int));
    int*   bex    = (int*)alloc(64 * sizeof(int));
    int*   csr    = (int*)alloc((size_t)TE * sizeof(int));
    float* al     = (float*)alloc((size_t)NN * 4 * sizeof(float));
    float* xs     = (float*)alloc((size_t)NN * 128 * sizeof(float));
    float* h      = (float*)alloc((size_t)NN * 128 * sizeof(float));
    (void)ws_size; (void)n_in; (void)in_sizes; (void)out_size;

    const int NB = (NN + 1023) / 1024;       // 49
    const int GEMM_GRID = (NN + 63) / 64;    // 782

    hipMemsetAsync(counts, 0, (size_t)NN * sizeof(int), stream);
    k_count<<<(TE + 255) / 256, 256, 0, stream>>>(ei, counts);
    k_bsum<<<NB, 1024, 0, stream>>>(counts, bsums);
    k_bscan<<<1, 64, 0, stream>>>(bsums, bex, NB);
    k_scan<<<NB, 1024, 0, stream>>>(counts, bex, rowptr, cursor);
    k_scatter<<<(TE + 255) / 256, 256, 0, stream>>>(ei, cursor, csr);

    k_gemm<<<GEMM_GRID, 256, 0, stream>>>(x, W1, as1, ad1, xs, al);
    k_agg<0><<<(NN + 3) / 4, 256, 0, stream>>>(xs, al, rowptr, csr, b1, nullptr, nullptr, pa, h);
    k_gemm<<<GEMM_GRID, 256, 0, stream>>>(h, W2, as2, ad2, xs, al);
    k_agg<0><<<(NN + 3) / 4, 256, 0, stream>>>(xs, al, rowptr, csr, b2, nullptr, nullptr, pa, h);
    k_gemm<<<GEMM_GRID, 256, 0, stream>>>(h, W3, as3, ad3, xs, al);
    k_agg<1><<<(NN + 3) / 4, 256, 0, stream>>>(xs, al, rowptr, csr, b3, lpw, lpb, pa, out);
}

// Round 7
// 392.491 us; speedup vs baseline: 1.6616x; 1.2940x over previous
//
#include <hip/hip_runtime.h>

#define NN 50000
#define NE 800000
#define TE (NE + NN)

__device__ __forceinline__ float lrelu02(float x) { return x >= 0.f ? x : 0.2f * x; }

__global__ void k_count(const int* __restrict__ ei, int* __restrict__ counts) {
    int e = blockIdx.x * blockDim.x + threadIdx.x;
    if (e >= TE) return;
    int dst = (e < NE) ? ei[NE + e] : (e - NE);
    atomicAdd(&counts[dst], 1);
}

__global__ void k_bsum(const int* __restrict__ counts, int* __restrict__ bsums) {
    __shared__ int sm[1024];
    int i = blockIdx.x * 1024 + threadIdx.x;
    sm[threadIdx.x] = (i < NN) ? counts[i] : 0;
    __syncthreads();
    for (int off = 512; off > 0; off >>= 1) {
        if ((int)threadIdx.x < off) sm[threadIdx.x] += sm[threadIdx.x + off];
        __syncthreads();
    }
    if (threadIdx.x == 0) bsums[blockIdx.x] = sm[0];
}

__global__ void k_bscan(const int* __restrict__ bsums, int* __restrict__ bex, int nb) {
    int l = threadIdx.x;
    int v = (l < nb) ? bsums[l] : 0;
    int orig = v;
    for (int d = 1; d < 64; d <<= 1) {
        int t = __shfl_up(v, d);
        if (l >= d) v += t;
    }
    if (l <= nb) bex[l] = v - orig;
}

__global__ void k_scan(const int* __restrict__ counts, const int* __restrict__ bex,
                       int* __restrict__ rowptr, int* __restrict__ cursor) {
    __shared__ int sm[1024];
    int t = threadIdx.x;
    int i = blockIdx.x * 1024 + t;
    int c = (i < NN) ? counts[i] : 0;
    sm[t] = c;
    __syncthreads();
    for (int off = 1; off < 1024; off <<= 1) {
        int v = (t >= off) ? sm[t - off] : 0;
        __syncthreads();
        sm[t] += v;
        __syncthreads();
    }
    int ex = bex[blockIdx.x] + sm[t] - c;
    if (i <= NN) rowptr[i] = ex;
    if (i < NN) cursor[i] = ex;
}

__global__ void k_scatter(const int* __restrict__ ei, int* __restrict__ cursor, int* __restrict__ csr) {
    int e = blockIdx.x * blockDim.x + threadIdx.x;
    if (e >= TE) return;
    int src, dst;
    if (e < NE) { src = ei[e]; dst = ei[NE + e]; }
    else { src = e - NE; dst = src; }
    int pos = atomicAdd(&cursor[dst], 1);
    csr[pos] = src;
}

// GEMM X[N,128] @ W[128,128] -> XS[N,128], plus AL[n] = {als0, als1, ald0, ald1}
// Round-3 structure EXACT (proven ~30us): no LDS; W from global (L2-hot 64 KiB),
// X rows via wave-uniform scalar loads. 4 waves x 8 rows = 32 rows/block, unroll 4.
__global__ __launch_bounds__(256) void k_gemm(const float* __restrict__ X, const float* __restrict__ W,
                                              const float* __restrict__ as_, const float* __restrict__ ad_,
                                              float* __restrict__ XS, float* __restrict__ AL) {
    int wv = __builtin_amdgcn_readfirstlane(threadIdx.x >> 6);
    int lane = threadIdx.x & 63;
    float a0 = as_[lane], a1 = as_[64 + lane];
    float d0 = ad_[lane], d1 = ad_[64 + lane];
    int row0 = blockIdx.x * 32 + wv * 8;
    if (row0 >= NN) return;   // NN % 8 == 0, full 8-row groups only
    float acc[8][2];
#pragma unroll
    for (int r = 0; r < 8; r++) { acc[r][0] = 0.f; acc[r][1] = 0.f; }
#pragma unroll 4
    for (int kk = 0; kk < 128; kk += 4) {
        float w0[4], w1[4];
#pragma unroll
        for (int i = 0; i < 4; i++) {
            w0[i] = W[(kk + i) * 128 + lane];
            w1[i] = W[(kk + i) * 128 + 64 + lane];
        }
#pragma unroll
        for (int r = 0; r < 8; r++) {
            float4 xv = *(const float4*)(X + (size_t)(row0 + r) * 128 + kk);
            acc[r][0] = fmaf(xv.x, w0[0], fmaf(xv.y, w0[1], fmaf(xv.z, w0[2], fmaf(xv.w, w0[3], acc[r][0]))));
            acc[r][1] = fmaf(xv.x, w1[0], fmaf(xv.y, w1[1], fmaf(xv.z, w1[2], fmaf(xv.w, w1[3], acc[r][1]))));
        }
    }
#pragma unroll
    for (int r = 0; r < 8; r++) {
        int row = row0 + r;
        XS[(size_t)row * 128 + lane] = acc[r][0];
        XS[(size_t)row * 128 + 64 + lane] = acc[r][1];
        float s0 = acc[r][0] * a0, s1 = acc[r][1] * a1;
        float t0 = acc[r][0] * d0, t1 = acc[r][1] * d1;
#pragma unroll
        for (int off = 32; off > 0; off >>= 1) {
            s0 += __shfl_xor(s0, off);
            s1 += __shfl_xor(s1, off);
            t0 += __shfl_xor(t0, off);
            t1 += __shfl_xor(t1, off);
        }
        if (lane == 0) {
            float4 v; v.x = s0; v.y = s1; v.z = t0; v.w = t1;
            *(float4*)(AL + (size_t)row * 4) = v;
        }
    }
}

// Aggregation: round-4 structure EXACT (proven 65us): one wave per dst node,
// whole-wave coalesced row gather (float2/lane = 512 B/instr), 8 independent
// edge loads in flight, uniform-index __shfl broadcasts (readlane), scalar
// tail. No segment-max (logits bounded, exp safe in fp32).
template <int LAST>
__global__ __launch_bounds__(256) void k_agg(const float* __restrict__ XS, const float* __restrict__ AL,
                                             const int* __restrict__ rowptr, const int* __restrict__ csr,
                                             const float* __restrict__ bias, const float* __restrict__ lp_w,
                                             const float* __restrict__ lp_b, const float* __restrict__ prelu_a,
                                             float* __restrict__ out) {
    int wv = threadIdx.x >> 6, lane = threadIdx.x & 63;
    int n = blockIdx.x * 4 + wv;
    if (n >= NN) return;
    int beg = rowptr[n], end = rowptr[n + 1];
    float2 aldv = *(const float2*)(AL + (size_t)n * 4 + 2);
    float ald0 = aldv.x, ald1 = aldv.y;
    float acc_lo = 0.f, acc_hi = 0.f, den0 = 0.f, den1 = 0.f;
    for (int base = beg; base < end; base += 64) {
        int i = base + lane;
        float w0 = 0.f, w1 = 0.f;
        int sv = 0;
        if (i < end) {
            sv = csr[i];
            float2 av = *(const float2*)(AL + (size_t)sv * 4);
            w0 = __expf(lrelu02(av.x + ald0));
            w1 = __expf(lrelu02(av.y + ald1));
        }
        den0 += w0;
        den1 += w1;
        int cnt = min(64, end - base);
        int j = 0;
        for (; j + 8 <= cnt; j += 8) {
            int s[8];
            float ww[8];
#pragma unroll
            for (int jj = 0; jj < 8; jj++) {
                s[jj] = __shfl(sv, j + jj);                       // uniform idx -> readlane
                float q0 = __shfl(w0, j + jj), q1 = __shfl(w1, j + jj);
                ww[jj] = (lane < 32) ? q0 : q1;
            }
            float2 xv[8];
#pragma unroll
            for (int jj = 0; jj < 8; jj++)
                xv[jj] = *(const float2*)(XS + (size_t)s[jj] * 128 + 2 * lane);
#pragma unroll
            for (int jj = 0; jj < 8; jj++) {
                acc_lo = fmaf(ww[jj], xv[jj].x, acc_lo);
                acc_hi = fmaf(ww[jj], xv[jj].y, acc_hi);
            }
        }
        for (; j < cnt; j++) {
            int s = __shfl(sv, j);
            float q0 = __shfl(w0, j), q1 = __shfl(w1, j);
            float w = (lane < 32) ? q0 : q1;
            float2 xv = *(const float2*)(XS + (size_t)s * 128 + 2 * lane);
            acc_lo = fmaf(w, xv.x, acc_lo);
            acc_hi = fmaf(w, xv.y, acc_hi);
        }
    }
#pragma unroll
    for (int off = 32; off > 0; off >>= 1) {
        den0 += __shfl_xor(den0, off);
        den1 += __shfl_xor(den1, off);
    }
    float pa = prelu_a[0];
    float densel = (lane < 32) ? den0 : den1;
    float inv = 1.f / (densel + 1e-16f);
    if (LAST) {
        float hlo = acc_lo * inv, hhi = acc_hi * inv;
        float olo = __shfl_xor(hlo, 32), ohi = __shfl_xor(hhi, 32);
        float p = 0.f;
        if (lane < 32) {
            int c = 2 * lane;
            float v0 = 0.5f * (hlo + olo) + bias[c];
            float v1 = 0.5f * (hhi + ohi) + bias[c + 1];
            v0 = v0 >= 0.f ? v0 : pa * v0;
            v1 = v1 >= 0.f ? v1 : pa * v1;
            p = v0 * lp_w[c] + v1 * lp_w[c + 1];
        }
#pragma unroll
        for (int off = 32; off > 0; off >>= 1) p += __shfl_xor(p, off);
        if (lane == 0) out[n] = p + lp_b[0];
    } else {
        int c = 2 * lane;
        float2 bv = *(const float2*)(bias + c);
        float v0 = acc_lo * inv + bv.x;
        float v1 = acc_hi * inv + bv.y;
        v0 = v0 >= 0.f ? v0 : pa * v0;
        v1 = v1 >= 0.f ? v1 : pa * v1;
        float2 o; o.x = v0; o.y = v1;
        *(float2*)(out + (size_t)n * 128 + c) = o;
    }
}

extern "C" void kernel_launch(void* const* d_in, const int* in_sizes, int n_in,
                              void* d_out, int out_size, void* d_ws, size_t ws_size,
                              hipStream_t stream) {
    const float* x   = (const float*)d_in[0];
    const int*   ei  = (const int*)d_in[1];
    const float* W1  = (const float*)d_in[2];
    const float* as1 = (const float*)d_in[3];
    const float* ad1 = (const float*)d_in[4];
    const float* b1  = (const float*)d_in[5];
    const float* W2  = (const float*)d_in[6];
    const float* as2 = (const float*)d_in[7];
    const float* ad2 = (const float*)d_in[8];
    const float* b2  = (const float*)d_in[9];
    const float* W3  = (const float*)d_in[10];
    const float* as3 = (const float*)d_in[11];
    const float* ad3 = (const float*)d_in[12];
    const float* b3  = (const float*)d_in[13];
    const float* lpw = (const float*)d_in[14];
    const float* lpb = (const float*)d_in[15];
    const float* pa  = (const float*)d_in[16];
    float* out = (float*)d_out;

    char* ws = (char*)d_ws;
    size_t off = 0;
    auto alloc = [&](size_t bytes) {
        void* p = ws + off;
        off = (off + bytes + 255) & ~(size_t)255;
        return p;
    };
    int*   rowptr = (int*)alloc((NN + 1) * sizeof(int));
    int*   cursor = (int*)alloc((NN + 1) * sizeof(int));
    int*   counts = (int*)alloc((size_t)NN * sizeof(int));
    int*   bsums  = (int*)alloc(64 * sizeof(int));
    int*   bex    = (int*)alloc(64 * sizeof(int));
    int*   csr    = (int*)alloc((size_t)TE * sizeof(int));
    float* al     = (float*)alloc((size_t)NN * 4 * sizeof(float));
    float* xs     = (float*)alloc((size_t)NN * 128 * sizeof(float));
    float* h      = (float*)alloc((size_t)NN * 128 * sizeof(float));
    (void)ws_size; (void)n_in; (void)in_sizes; (void)out_size;

    const int NB = (NN + 1023) / 1024;       // 49
    const int GEMM_GRID = (NN + 31) / 32;    // 1563

    hipMemsetAsync(counts, 0, (size_t)NN * sizeof(int), stream);
    k_count<<<(TE + 255) / 256, 256, 0, stream>>>(ei, counts);
    k_bsum<<<NB, 1024, 0, stream>>>(counts, bsums);
    k_bscan<<<1, 64, 0, stream>>>(bsums, bex, NB);
    k_scan<<<NB, 1024, 0, stream>>>(counts, bex, rowptr, cursor);
    k_scatter<<<(TE + 255) / 256, 256, 0, stream>>>(ei, cursor, csr);

    k_gemm<<<GEMM_GRID, 256, 0, stream>>>(x, W1, as1, ad1, xs, al);
    k_agg<0><<<(NN + 3) / 4, 256, 0, stream>>>(xs, al, rowptr, csr, b1, nullptr, nullptr, pa, h);
    k_gemm<<<GEMM_GRID, 256, 0, stream>>>(h, W2, as2, ad2, xs, al);
    k_agg<0><<<(NN + 3) / 4, 256, 0, stream>>>(xs, al, rowptr, csr, b2, nullptr, nullptr, pa, h);
    k_gemm<<<GEMM_GRID, 256, 0, stream>>>(h, W3, as3, ad3, xs, al);
    k_agg<1><<<(NN + 3) / 4, 256, 0, stream>>>(xs, al, rowptr, csr, b3, lpw, lpb, pa, out);
}